// Round 8
// baseline (975.950 us; speedup 1.0000x reference)
//
#include <hip/hip_runtime.h>
#include <math.h>

// Problem constants
#define DD 256            // latent dim
#define KK 8192           // codebook size
#define NN 16384          // rows
#define MT 16             // rows per block (2 row-groups x 8, K-split 2-way)
#define RPW 8             // rows per wave
#define NT 512            // cols per chunk (lane + 64*j, j 0..7)
#define NCHG 8            // chunks per col-group (16 total / 2 groups)
#define NBM (NN / MT)     // 1024 main blocks x 256 thr
#define NBLOCKS 512       // gather/partial grid (verified 32-row geometry)
#define RSTRIDE 260       // rowsumsq staging stride (unchanged, verified)

// Output layout (all float32, concatenated in reference return order)
#define OUT_IDS   0
#define OUT_Q     16384
#define OUT_ST    4210688          // 16384 + 4194304
#define OUT_COMMIT 8404992
#define OUT_CBL    8404993
#define OUT_PERP   8404994

// ---------------------------------------------------------------------------
// numpy pairwise-sum replica for sum of squares (verified bit-exact)
// ---------------------------------------------------------------------------
__device__ __forceinline__ float np_block128_sumsq(const float* p) {
    #pragma clang fp contract(off)
    float r0 = p[0] * p[0], r1 = p[1] * p[1], r2 = p[2] * p[2], r3 = p[3] * p[3];
    float r4 = p[4] * p[4], r5 = p[5] * p[5], r6 = p[6] * p[6], r7 = p[7] * p[7];
    for (int i = 8; i < 128; i += 8) {
        r0 = r0 + p[i + 0] * p[i + 0];
        r1 = r1 + p[i + 1] * p[i + 1];
        r2 = r2 + p[i + 2] * p[i + 2];
        r3 = r3 + p[i + 3] * p[i + 3];
        r4 = r4 + p[i + 4] * p[i + 4];
        r5 = r5 + p[i + 5] * p[i + 5];
        r6 = r6 + p[i + 6] * p[i + 6];
        r7 = r7 + p[i + 7] * p[i + 7];
    }
    return ((r0 + r1) + (r2 + r3)) + ((r4 + r5) + (r6 + r7));
}

__device__ __forceinline__ float np_pairwise256_sumsq(const float* a) {
    #pragma clang fp contract(off)
    float s0 = np_block128_sumsq(a);
    float s1 = np_block128_sumsq(a + 128);
    return s0 + s1;
}

// ---------------------------------------------------------------------------
// Kernel 1: per-row sum of squares, numpy-pairwise-exact (unchanged, verified)
// ---------------------------------------------------------------------------
__global__ __launch_bounds__(256) void rowsumsq(const float* __restrict__ A,
                                                float* __restrict__ out) {
    __shared__ __align__(16) float sA[64][RSTRIDE];
    const int tid = threadIdx.x;
    const int base = blockIdx.x * 64;
    #pragma unroll
    for (int i = 0; i < 16; ++i) {
        int g = i * 256 + tid;
        int row = g >> 6, d4 = g & 63;
        float4 v = reinterpret_cast<const float4*>(A)[(size_t)(base + row) * (DD / 4) + d4];
        *reinterpret_cast<float4*>(&sA[row][d4 * 4]) = v;
    }
    __syncthreads();
    if (tid < 64) out[base + tid] = np_pairwise256_sumsq(sA[tid]);
}

// ---------------------------------------------------------------------------
// Kernel 1b: codebook transpose into d4-plane-major layout (R6, verified).
//   CBt[p*8192 + col] (float4) = CB[col][4p .. 4p+3]   (p = 0..63)
//   Bit-exact copy; enables coalesced per-lane codebook reads.
// ---------------------------------------------------------------------------
__global__ __launch_bounds__(256) void cb_transpose(const float* __restrict__ CB,
                                                    float4* __restrict__ CBt) {
    const int id = blockIdx.x * 256 + threadIdx.x;   // 0 .. 64*8192-1
    const int p   = id >> 13;
    const int col = id & (KK - 1);
    CBt[id] = *reinterpret_cast<const float4*>(CB + (size_t)col * DD + p * 4);
}

// ---------------------------------------------------------------------------
// Kernel 1c: X transpose into the same plane-major layout (ROUND-8, new).
//   Xt[p*16384 + row] (float4) = X[row][4p .. 4p+3]   (p = 0..63)
//   Bit-exact copy. A wave's 8-row X slice per plane becomes 32 CONTIGUOUS
//   uniform floats -> 2 merged s_load_dwordx16 (vs 8 strided s_load_dwordx4),
//   and the per-wave slice (8 KB, identical across chunks) is K$-resident.
//   Xt lives in out+OUT_ST scratch (exactly 4,194,304 floats);
//   vq_gather overwrites every element of that region afterwards.
// ---------------------------------------------------------------------------
__global__ __launch_bounds__(256) void x_transpose(const float* __restrict__ X,
                                                   float4* __restrict__ Xt) {
    const int id = blockIdx.x * 256 + threadIdx.x;   // 0 .. 64*16384-1
    const int p   = id >> 14;
    const int row = id & (NN - 1);
    Xt[id] = *reinterpret_cast<const float4*>(X + (size_t)row * DD + p * 4);
}

// ---------------------------------------------------------------------------
// Kernel 2: main VQ distance+argmin — barrier-free streaming (R6/R7) plus
//   ROUND-8: latency-proof register pipeline at the pinned 2 waves/SIMD.
//   Evidence: R1/R4/R7 pin residency at 2 waves/SIMD for this kernel unless
//   arg2=4 (fatal 64-VGPR cap). So VGPRs are FREE to 256 (m69) — spend them:
//   (a) cc DOUBLE-BUFFER (ccA/ccB): loads for plane p+1 issue BEFORE plane
//       p's 256-fma block -> every load has a full 512-cycle fma window to
//       cover ~300-cycle L2 latency, guaranteed across loop iterations
//       (R6/R7's runtime b-loop blocked this hoisting). Static names, all
//       indices compile-time (no runtime-indexed arrays -> no scratch).
//   (b) running pointers pA/pB += 2*KK replace per-step p*KK 64-bit mul
//       chains; j-offsets become immediate-foldable constants.
//   (c) X scalars from Xt (plane-major): 2 merged s_loads per plane, K$-hot.
//   Loads are reordered ONLY; the per-(row,col) fp32 fma chain stays
//   d=0..255 in x/y/z/w order; score fl(fl(x2+c2)-2m); first-index ties;
//   butterfly argmin; strict-less cross-group merge — all bit-exact,
//   verified structure from R5/R6/R7 (absmax 0.0).
//   NO launch_bounds arg2 (arg2 caps VGPR at 256/arg2 — R0-R5 law).
// ---------------------------------------------------------------------------
#define LOADCC(dst, ptr) do {                                                  \
    _Pragma("unroll")                                                          \
    for (int j_ = 0; j_ < 8; ++j_) (dst)[j_] = (ptr)[64 * j_];                 \
} while (0)

#define FMASTEP(cc, xs) do {                                                   \
    _Pragma("unroll")                                                          \
    for (int rr_ = 0; rr_ < 8; ++rr_) {                                        \
        const float sx_ = (xs)[rr_ * 4 + 0];                                   \
        const float sy_ = (xs)[rr_ * 4 + 1];                                   \
        const float sz_ = (xs)[rr_ * 4 + 2];                                   \
        const float sw_ = (xs)[rr_ * 4 + 3];                                   \
        _Pragma("unroll")                                                      \
        for (int j_ = 0; j_ < 8; ++j_) {                                       \
            acc[rr_][j_] = fmaf(sx_, (cc)[j_].x, acc[rr_][j_]);                \
            acc[rr_][j_] = fmaf(sy_, (cc)[j_].y, acc[rr_][j_]);                \
            acc[rr_][j_] = fmaf(sz_, (cc)[j_].z, acc[rr_][j_]);                \
            acc[rr_][j_] = fmaf(sw_, (cc)[j_].w, acc[rr_][j_]);                \
        }                                                                      \
    }                                                                          \
} while (0)

__global__ __launch_bounds__(256) void vq_main(const float4* __restrict__ Xt,
                                               const float4* __restrict__ CBt,
                                               const float* __restrict__ c2,
                                               const float* __restrict__ x2,
                                               const float* __restrict__ mask,
                                               float* __restrict__ out,
                                               float* __restrict__ hist) {
    __shared__ float gbest[2][MT];
    __shared__ int   gidx[2][MT];

    const int tid  = threadIdx.x;
    const int lane = tid & 63;
    const int wid  = tid >> 6;                                  // 0..3
    const int widu = __builtin_amdgcn_readfirstlane(wid);       // uniform copy
    const int g    = wid >> 1;        // col-group (0: cols 0..4095, 1: 4096..8191)
    const int gu   = widu >> 1;
    const int wg   = wid & 1;         // row-group (8 rows each)
    const int wgu  = widu & 1;
    const int block_row = blockIdx.x * MT;

    // uniform X base in plane-major Xt: plane stride = NN floats4 = NN*4 floats
    const float* xbase = reinterpret_cast<const float*>(Xt)
                       + (size_t)(block_row + wgu * RPW) * 4;

    // row constants (bit-identical to numpy's x2)
    float x2r[RPW];
    #pragma unroll
    for (int rr = 0; rr < RPW; ++rr) x2r[rr] = x2[block_row + wg * RPW + rr];

    float best[RPW];
    int   besti[RPW];
    #pragma unroll
    for (int rr = 0; rr < RPW; ++rr) { best[rr] = 3.4e38f; besti[rr] = 0; }

    const float4* cbt_lane = CBt + lane;      // per-lane column offset

    for (int ch = 0; ch < NCHG; ++ch) {
        const int chg = gu * NCHG + ch;       // global chunk id (uniform)
        float c2v[8];
        #pragma unroll
        for (int j = 0; j < 8; ++j) c2v[j] = c2[chg * NT + lane + 64 * j];

        float acc[8][8];
        #pragma unroll
        for (int rr = 0; rr < 8; ++rr)
            #pragma unroll
            for (int j = 0; j < 8; ++j) acc[rr][j] = 0.0f;

        // software-pipelined plane walk: ccA = even planes, ccB = odd planes
        float4 ccA[8], ccB[8];
        const float4* pA = cbt_lane + (size_t)chg * NT;          // plane 0
        const float4* pB = pA + KK;                              // plane 1
        const float*  xs = xbase;                                // plane 0 X

        LOADCC(ccA, pA);                       // prologue: plane 0 in flight
        for (int pb = 0; pb < 31; ++pb) {      // planes 2pb and 2pb+1
            LOADCC(ccB, pB);                   // issue plane 2pb+1
            FMASTEP(ccA, xs);                  // compute plane 2pb
            pA += 2 * KK;
            LOADCC(ccA, pA);                   // issue plane 2pb+2
            FMASTEP(ccB, xs + NN * 4);         // compute plane 2pb+1
            pB += 2 * KK;
            xs += 2 * NN * 4;
        }
        LOADCC(ccB, pB);                       // plane 63
        FMASTEP(ccA, xs);                      // plane 62
        FMASTEP(ccB, xs + NN * 4);             // plane 63

        // ---- fp32 distance exactly as numpy, then argmin (first-index ties) ----
        #pragma unroll
        for (int rr = 0; rr < 8; ++rr) {
            #pragma unroll
            for (int j = 0; j < 8; ++j) {
                const int col = chg * NT + lane + 64 * j;
                float t1 = x2r[rr] + c2v[j];
                float sc = t1 - 2.0f * acc[rr][j];
                if (sc < best[rr] || (sc == best[rr] && col < besti[rr])) {
                    best[rr] = sc; besti[rr] = col;
                }
            }
        }
    }

    // ---- per-row argmin across the wave's 64 lanes (xor butterfly) ----
    #pragma unroll
    for (int rr = 0; rr < RPW; ++rr) {
        float b = best[rr];
        int  bi = besti[rr];
        #pragma unroll
        for (int m = 32; m > 0; m >>= 1) {
            float b2 = __shfl_xor(b, m, 64);
            int   i2 = __shfl_xor(bi, m, 64);
            if (b2 < b || (b2 == b && i2 < bi)) { b = b2; bi = i2; }
        }
        if (lane == 0) {
            gbest[g][wg * RPW + rr] = b;
            gidx [g][wg * RPW + rr] = bi;
        }
    }
    __syncthreads();   // the only block-wide barrier

    // ---- cross-group merge: group 0 has lower cols, so tie -> group 0 ----
    if (tid < MT) {
        const float b0 = gbest[0][tid], b1 = gbest[1][tid];
        const int bi = (b1 < b0) ? gidx[1][tid] : gidx[0][tid];
        out[OUT_IDS + block_row + tid] = (float)bi;   // exact integer in float
        atomicAdd(&hist[bi], mask[block_row + tid]);  // mask=1.0 -> order-exact
    }
}

// ---------------------------------------------------------------------------
// Kernel 2b: gather + MSE partials. 512 blocks x 256 threads, VERBATIM the
//   verified R0 epilogue -> partial[512] and outq/outst bit-identical.
//   Overwrites BOTH scratch regions (CBt in OUT_Q, Xt in OUT_ST) entirely.
// ---------------------------------------------------------------------------
__global__ __launch_bounds__(256) void vq_gather(const float* __restrict__ X,
                                                 const float* __restrict__ CB,
                                                 float* __restrict__ out,
                                                 float* __restrict__ partial) {
    __shared__ int   row_id[32];
    __shared__ float wsum[4];
    const int tid  = threadIdx.x;
    const int lane = tid & 63;
    const int wid  = tid >> 6;
    const int block_row = blockIdx.x * 32;

    if (tid < 32) row_id[tid] = (int)out[OUT_IDS + block_row + tid];
    __syncthreads();

    float msep = 0.0f;
    float* outq  = out + OUT_Q;
    float* outst = out + OUT_ST;
    #pragma unroll
    for (int i = 0; i < 8; ++i) {
        int g2 = i * 256 + tid;         // 0..2047 covers 32 rows x 64 float4
        int row = g2 >> 6;
        int d4  = g2 & 63;
        int id  = row_id[row];
        float4 q = reinterpret_cast<const float4*>(CB)[(size_t)id * (DD / 4) + d4];
        float4 x = reinterpret_cast<const float4*>(X)[(size_t)(block_row + row) * (DD / 4) + d4];
        float4 st;
        st.x = x.x + (q.x - x.x);
        st.y = x.y + (q.y - x.y);
        st.z = x.z + (q.z - x.z);
        st.w = x.w + (q.w - x.w);
        float dx = x.x - q.x; msep = fmaf(dx, dx, msep);
        dx = x.y - q.y; msep = fmaf(dx, dx, msep);
        dx = x.z - q.z; msep = fmaf(dx, dx, msep);
        dx = x.w - q.w; msep = fmaf(dx, dx, msep);
        size_t o = (size_t)(block_row + row) * (DD / 4) + d4;
        reinterpret_cast<float4*>(outq)[o]  = q;
        reinterpret_cast<float4*>(outst)[o] = st;
    }
    #pragma unroll
    for (int off = 32; off > 0; off >>= 1) msep += __shfl_down(msep, off, 64);
    if (lane == 0) wsum[wid] = msep;
    __syncthreads();
    if (tid == 0) partial[blockIdx.x] = wsum[0] + wsum[1] + wsum[2] + wsum[3];
}

// ---------------------------------------------------------------------------
// Kernel 3: finalize losses + perplexity (double precision, single block)
// ---------------------------------------------------------------------------
__global__ __launch_bounds__(256) void vq_finalize(const float* __restrict__ partial,
                                                   const float* __restrict__ hist,
                                                   float* __restrict__ out) {
    __shared__ double red[256];
    const int tid = threadIdx.x;

    double ps = 0.0;
    for (int j = tid; j < NBLOCKS; j += 256) ps += (double)partial[j];
    red[tid] = ps;
    __syncthreads();
    for (int s = 128; s > 0; s >>= 1) {
        if (tid < s) red[tid] += red[tid + s];
        __syncthreads();
    }
    double mse_sum = red[0];
    __syncthreads();

    double hs = 0.0;
    for (int j = tid; j < KK; j += 256) hs += (double)hist[j];
    red[tid] = hs;
    __syncthreads();
    for (int s = 128; s > 0; s >>= 1) {
        if (tid < s) red[tid] += red[tid + s];
        __syncthreads();
    }
    double denom = red[0] > 1.0 ? red[0] : 1.0;
    __syncthreads();

    double ent = 0.0;
    for (int j = tid; j < KK; j += 256) {
        double p = (double)hist[j] / denom;
        ent += p * log(p + 1e-8);
    }
    red[tid] = ent;
    __syncthreads();
    for (int s = 128; s > 0; s >>= 1) {
        if (tid < s) red[tid] += red[tid + s];
        __syncthreads();
    }

    if (tid == 0) {
        double mse = mse_sum / (double)((size_t)NN * DD);
        out[OUT_COMMIT] = (float)(mse * 0.25);
        out[OUT_CBL]    = (float)mse;
        out[OUT_PERP]   = (float)exp(-red[0]);
    }
}

// ---------------------------------------------------------------------------
extern "C" void kernel_launch(void* const* d_in, const int* in_sizes, int n_in,
                              void* d_out, int out_size, void* d_ws, size_t ws_size,
                              hipStream_t stream) {
    const float* latents = (const float*)d_in[0];   // [16,1024,256]
    const float* mask    = (const float*)d_in[1];   // [16,1024]
    const float* cb      = (const float*)d_in[2];   // [8192,256]
    float* out = (float*)d_out;

    // workspace layout (floats): hist[8192] | partial[512] | c2[8192] | x2[16384]
    float* hist    = (float*)d_ws;
    float* partial = hist + KK;
    float* c2      = partial + NBLOCKS;
    float* x2      = c2 + KK;

    // scratch in the out buffer, both fully overwritten by vq_gather:
    //   CBt (2,097,152 floats) in the OUT_Q region (4,194,304 floats)
    //   Xt  (4,194,304 floats) in the OUT_ST region (exactly fits)
    float4* cbt = reinterpret_cast<float4*>(out + OUT_Q);
    float4* xt  = reinterpret_cast<float4*>(out + OUT_ST);

    hipMemsetAsync(d_ws, 0, KK * sizeof(float), stream);    // zero histogram
    rowsumsq<<<KK / 64, 256, 0, stream>>>(cb, c2);           // numpy-exact |c|^2
    rowsumsq<<<NN / 64, 256, 0, stream>>>(latents, x2);      // numpy-exact |x|^2
    cb_transpose<<<(64 * KK) / 256, 256, 0, stream>>>(cb, cbt);
    x_transpose<<<(64 * NN) / 256, 256, 0, stream>>>(latents, xt);
    vq_main<<<NBM, 256, 0, stream>>>(xt, cbt, c2, x2, mask, out, hist);
    vq_gather<<<NBLOCKS, 256, 0, stream>>>(latents, cb, out, partial);
    vq_finalize<<<1, 256, 0, stream>>>(partial, hist, out);
}